// Round 1
// baseline (32.274 us; speedup 1.0000x reference)
//
#include <hip/hip_runtime.h>

#define NUM_CLASS 121
#define BROWS 262144

// One thread per row. Each row contributes
//   sum_{j=0..4, c=label+j-2 in [0,C)} -kweight[j] * log(pred[row,c] + 1e-8)
// Reduce wave (64) -> block (256) -> global atomicAdd of pre-scaled partial.
__global__ __launch_bounds__(256)
void sce_kernel(const float* __restrict__ pred,
                const int*   __restrict__ label,
                const float* __restrict__ kw,
                float*       __restrict__ out) {
    const int row = blockIdx.x * blockDim.x + threadIdx.x;

    // kweight: uniform address -> scalar-cached broadcast loads
    const float w0 = kw[0], w1 = kw[1], w2 = kw[2], w3 = kw[3], w4 = kw[4];

    float acc = 0.0f;
    if (row < BROWS) {
        const int lab = label[row];
        const float* __restrict__ p = pred + (size_t)row * NUM_CLASS;
        const float w[5] = {w0, w1, w2, w3, w4};
        #pragma unroll
        for (int j = 0; j < 5; ++j) {
            const int c = lab + j - 2;
            if (c >= 0 && c < NUM_CLASS) {
                acc -= w[j] * logf(p[c] + 1e-8f);
            }
        }
    }

    // wave-64 butterfly reduce
    #pragma unroll
    for (int off = 32; off > 0; off >>= 1)
        acc += __shfl_down(acc, off, 64);

    __shared__ float wsum[4];
    const int lane = threadIdx.x & 63;
    const int wid  = threadIdx.x >> 6;
    if (lane == 0) wsum[wid] = acc;
    __syncthreads();

    if (threadIdx.x == 0) {
        const float s = wsum[0] + wsum[1] + wsum[2] + wsum[3];
        // pre-scale by 1/(B*C) so the atomic target stays O(1e-2)
        atomicAdd(out, s * (1.0f / ((float)BROWS * (float)NUM_CLASS)));
    }
}

extern "C" void kernel_launch(void* const* d_in, const int* in_sizes, int n_in,
                              void* d_out, int out_size, void* d_ws, size_t ws_size,
                              hipStream_t stream) {
    const float* pred  = (const float*)d_in[0];
    const int*   label = (const int*)d_in[1];
    const float* kw    = (const float*)d_in[2];
    float*       out   = (float*)d_out;

    // d_out is poisoned (0xAA) before timing and never re-poisoned between
    // replays -> must zero it ourselves every call (capture-safe memset).
    hipMemsetAsync(out, 0, sizeof(float), stream);

    const int threads = 256;
    const int blocks  = BROWS / threads;  // 262144 / 256 = 1024
    sce_kernel<<<blocks, threads, 0, stream>>>(pred, label, kw, out);
}

// Round 2
// 15.324 us; speedup vs baseline: 2.1061x; 2.1061x over previous
//
#include <hip/hip_runtime.h>

#define NUM_CLASS 121
#define BROWS 262144
#define THREADS 256
#define BLOCKS (BROWS / THREADS)   // 1024

// Kernel 1: one thread per row. Each row contributes
//   sum_{j=0..4, c=label+j-2 in [0,C)} -kweight[j] * log(pred[row,c] + 1e-8)
// Block-reduce -> plain store of one partial per block (no atomics, no
// pre-zeroed memory needed: every slot is overwritten every call).
__global__ __launch_bounds__(THREADS)
void sce_partial(const float* __restrict__ pred,
                 const int*   __restrict__ label,
                 const float* __restrict__ kw,
                 float*       __restrict__ partial) {
    const int row = blockIdx.x * THREADS + threadIdx.x;  // grid covers BROWS exactly

    const float w0 = kw[0], w1 = kw[1], w2 = kw[2], w3 = kw[3], w4 = kw[4];
    const float w[5] = {w0, w1, w2, w3, w4};

    const int lab = label[row];
    const float* __restrict__ p = pred + (size_t)row * NUM_CLASS;

    float acc = 0.0f;
    #pragma unroll
    for (int j = 0; j < 5; ++j) {
        const int  c  = lab + j - 2;
        const bool ok = (c >= 0) & (c < NUM_CLASS);
        const int  cc = ok ? c : 0;          // clamped: load always executes
        const float wj = ok ? w[j] : 0.0f;   // predicated weight, no divergence
        acc -= wj * logf(p[cc] + 1e-8f);
    }

    // wave-64 butterfly reduce
    #pragma unroll
    for (int off = 32; off > 0; off >>= 1)
        acc += __shfl_down(acc, off, 64);

    __shared__ float wsum[THREADS / 64];
    const int lane = threadIdx.x & 63;
    const int wid  = threadIdx.x >> 6;
    if (lane == 0) wsum[wid] = acc;
    __syncthreads();

    if (threadIdx.x == 0)
        partial[blockIdx.x] = wsum[0] + wsum[1] + wsum[2] + wsum[3];
}

// Kernel 2: single block reduces BLOCKS partials, scales, stores the scalar.
__global__ __launch_bounds__(THREADS)
void sce_reduce(const float* __restrict__ partial,
                float*       __restrict__ out) {
    float acc = 0.0f;
    #pragma unroll
    for (int i = threadIdx.x; i < BLOCKS; i += THREADS)
        acc += partial[i];

    #pragma unroll
    for (int off = 32; off > 0; off >>= 1)
        acc += __shfl_down(acc, off, 64);

    __shared__ float wsum[THREADS / 64];
    const int lane = threadIdx.x & 63;
    const int wid  = threadIdx.x >> 6;
    if (lane == 0) wsum[wid] = acc;
    __syncthreads();

    if (threadIdx.x == 0) {
        const float s = wsum[0] + wsum[1] + wsum[2] + wsum[3];
        out[0] = s * (1.0f / ((float)BROWS * (float)NUM_CLASS));
    }
}

extern "C" void kernel_launch(void* const* d_in, const int* in_sizes, int n_in,
                              void* d_out, int out_size, void* d_ws, size_t ws_size,
                              hipStream_t stream) {
    const float* pred  = (const float*)d_in[0];
    const int*   label = (const int*)d_in[1];
    const float* kw    = (const float*)d_in[2];
    float*       out   = (float*)d_out;
    float*       part  = (float*)d_ws;       // needs BLOCKS*4 = 4 KiB of scratch

    sce_partial<<<BLOCKS, THREADS, 0, stream>>>(pred, label, kw, part);
    sce_reduce<<<1, THREADS, 0, stream>>>(part, out);
}